// Round 11
// baseline (174.081 us; speedup 1.0000x reference)
//
#include <hip/hip_runtime.h>
#include <hip/hip_bf16.h>
#include <math.h>

// GCN 2-hop + linear(64->2) + log_softmax, N=100000, E=1600000, D=64.
//
// R10 lessons: (1) hipMemsetAsync inside the graph costs ~43us FIXED (tiny
// fill showed 44us @ 15KB) -> replaced with a 1-block zero kernel. (2) part
// write amplification at 782 buckets (3.3-edge chunks) = 39MB HBM write ->
// back to 391 buckets (16-edge = 64B full-line chunks) + nontemporal stores.
// (3) hops need 24 waves/CU (391 blocks x 1024 thr) to hide L3-latency
// gathers; keep R10's 8B v2 = dinv*u gather payload.
//
// Math (verified R8-R10): u = x@W^T; d = rsqrt(indeg+1); v = d*u;
//   z = d^2*(v_self + sum v_src); logit = d*(z_self + sum z_src)+b;
//   out = log_softmax(logit).

#define NODES 100000
#define EDGES 1600000
#define DIM 64

#define PBITS 8
#define PSIZE 256
#define P_BUCKETS 391  // ceil(100000/256)
#define CAP 8192       // edges per bucket (mean 4092, huge headroom)

#define PART_BLOCKS 256
#define PART_PAIRS (EDGES / 2 / PART_BLOCKS)  // 3125 pairs per block

#define PROJ_BLOCKS 782
#define NODES_PER_PROJ 128
#define K1_BLOCKS (PART_BLOCKS + PROJ_BLOCKS)

// ---------------------------------------------------------------------------
__global__ void zero_kernel(int* __restrict__ cursor) {
  int i = threadIdx.x;
  if (i < P_BUCKETS) cursor[i] = 0;
}

// ---------------------------------------------------------------------------
// K1: role-split partition (blocks [0,256)) + projection (blocks [256,1038)).
__global__ __launch_bounds__(256) void partproj_kernel(
    const void* __restrict__ ei, int* __restrict__ cursor,
    int* __restrict__ ecbuf, const float* __restrict__ x,
    const float* __restrict__ W, float2* __restrict__ u) {
  const int t = threadIdx.x;
  if (blockIdx.x < PART_BLOCKS) {
    // ---------------- partition role ----------------
    __shared__ int shMode;
    __shared__ int lcnt[P_BUCKETS];
    __shared__ int lbase[P_BUCKETS];
    if (t < 64) {
      const int* p = (const int*)ei;
      unsigned long long ball = __ballot(p[2 * t + 1] == 0);
      if (t == 0) shMode = (ball == ~0ULL) ? 1 : 0;
    }
    for (int i = t; i < P_BUCKETS; i += 256) lcnt[i] = 0;
    __syncthreads();
    const int m = shMode;
    const int pbase = blockIdx.x * PART_PAIRS;

    // pass 1: count targets
    if (m) {
      const longlong2* cp =
          (const longlong2*)((const long long*)ei + EDGES) + pbase;
      for (int i = t; i < PART_PAIRS; i += 256) {
        longlong2 v = cp[i];
        atomicAdd(&lcnt[((int)v.x) >> PBITS], 1);
        atomicAdd(&lcnt[((int)v.y) >> PBITS], 1);
      }
    } else {
      const int2* cp = (const int2*)((const int*)ei + EDGES) + pbase;
      for (int i = t; i < PART_PAIRS; i += 256) {
        int2 v = cp[i];
        atomicAdd(&lcnt[v.x >> PBITS], 1);
        atomicAdd(&lcnt[v.y >> PBITS], 1);
      }
    }
    __syncthreads();
    // reserve per-bucket chunks
    for (int i = t; i < P_BUCKETS; i += 256) {
      int c = lcnt[i];
      lbase[i] = c ? atomicAdd(&cursor[i], c) : 0;
      lcnt[i] = 0;  // reuse as local rank cursor
    }
    __syncthreads();

    // pass 2: write packed edges (src<<8 | local_col), nontemporal
    if (m) {
      const longlong2* rp = (const longlong2*)ei + pbase;
      const longlong2* cp =
          (const longlong2*)((const long long*)ei + EDGES) + pbase;
      for (int i = t; i < PART_PAIRS; i += 256) {
        longlong2 rv = rp[i];
        longlong2 cv = cp[i];
        {
          int r = (int)rv.x, c = (int)cv.x, bk = c >> PBITS;
          int rel = lbase[bk] + atomicAdd(&lcnt[bk], 1);
          if (rel < CAP)
            __builtin_nontemporal_store((r << PBITS) | (c & (PSIZE - 1)),
                                        &ecbuf[bk * CAP + rel]);
        }
        {
          int r = (int)rv.y, c = (int)cv.y, bk = c >> PBITS;
          int rel = lbase[bk] + atomicAdd(&lcnt[bk], 1);
          if (rel < CAP)
            __builtin_nontemporal_store((r << PBITS) | (c & (PSIZE - 1)),
                                        &ecbuf[bk * CAP + rel]);
        }
      }
    } else {
      const int2* rp = (const int2*)ei + pbase;
      const int2* cp = (const int2*)((const int*)ei + EDGES) + pbase;
      for (int i = t; i < PART_PAIRS; i += 256) {
        int2 rv = rp[i];
        int2 cv = cp[i];
        {
          int bk = cv.x >> PBITS;
          int rel = lbase[bk] + atomicAdd(&lcnt[bk], 1);
          if (rel < CAP)
            __builtin_nontemporal_store((rv.x << PBITS) | (cv.x & (PSIZE - 1)),
                                        &ecbuf[bk * CAP + rel]);
        }
        {
          int bk = cv.y >> PBITS;
          int rel = lbase[bk] + atomicAdd(&lcnt[bk], 1);
          if (rel < CAP)
            __builtin_nontemporal_store((rv.y << PBITS) | (cv.y & (PSIZE - 1)),
                                        &ecbuf[bk * CAP + rel]);
        }
      }
    }
  } else {
    // ---------------- projection role: u[i] = x[i] @ W^T ----------------
    const int nbase = (blockIdx.x - PART_BLOCKS) * NODES_PER_PROJ;
    const int lane16 = t & 15;  // feature quad within node
    const int sub = t >> 4;     // 16 node-slots per pass
    const float4 w0 = *(const float4*)&W[lane16 * 4];
    const float4 w1 = *(const float4*)&W[DIM + lane16 * 4];
    for (int k = sub; k < NODES_PER_PROJ; k += 16) {
      const int node = nbase + k;
      if (node < NODES) {  // uniform within each 16-lane group
        float4 xv = *(const float4*)&x[(size_t)node * DIM + lane16 * 4];
        float p0 = xv.x * w0.x + xv.y * w0.y + xv.z * w0.z + xv.w * w0.w;
        float p1 = xv.x * w1.x + xv.y * w1.y + xv.z * w1.z + xv.w * w1.w;
#pragma unroll
        for (int off = 8; off >= 1; off >>= 1) {
          p0 += __shfl_xor(p0, off, 16);
          p1 += __shfl_xor(p1, off, 16);
        }
        if (lane16 == 0) u[node] = make_float2(p0, p1);
      }
    }
  }
}

// ---------------------------------------------------------------------------
// K2: per-bucket degree histogram -> dv = rsqrt(deg+1), v2 = dv*u. 1024 thr.
__global__ __launch_bounds__(1024) void deg_kernel(
    const int* __restrict__ cursor, const int* __restrict__ ecbuf,
    const float2* __restrict__ u, float2* __restrict__ v2,
    float* __restrict__ dv) {
  __shared__ int h[PSIZE];
  const int b = blockIdx.x;
  const int t = threadIdx.x;
  if (t < PSIZE) h[t] = 0;
  __syncthreads();
  const int cnt = min(cursor[b], CAP);
  const int4* ep4 = (const int4*)(ecbuf + b * CAP);
  for (int i = t; 4 * i < cnt; i += 1024) {
    int4 v = ep4[i];
    int base = 4 * i;
    if (base + 0 < cnt) atomicAdd(&h[v.x & (PSIZE - 1)], 1);
    if (base + 1 < cnt) atomicAdd(&h[v.y & (PSIZE - 1)], 1);
    if (base + 2 < cnt) atomicAdd(&h[v.z & (PSIZE - 1)], 1);
    if (base + 3 < cnt) atomicAdd(&h[v.w & (PSIZE - 1)], 1);
  }
  __syncthreads();
  if (t < PSIZE) {
    const int node = (b << PBITS) + t;
    if (node < NODES) {
      float d = rsqrtf((float)(h[t] + 1));
      float2 uu = u[node];
      dv[node] = d;
      v2[node] = make_float2(d * uu.x, d * uu.y);
    }
  }
}

// ---------------------------------------------------------------------------
// K3: hop 1. z = d^2 * (v_self + sum v_src). 8B gathers, 1024 thr.
__global__ __launch_bounds__(1024) void hop1_kernel(
    const int* __restrict__ cursor, const int* __restrict__ ecbuf,
    const float2* __restrict__ v2, const float* __restrict__ dv,
    float2* __restrict__ z) {
  __shared__ float ax[PSIZE];
  __shared__ float ay[PSIZE];
  const int b = blockIdx.x;
  const int t = threadIdx.x;
  if (t < PSIZE) {
    ax[t] = 0.f;
    ay[t] = 0.f;
  }
  __syncthreads();
  const int cnt = min(cursor[b], CAP);
  const int4* ep4 = (const int4*)(ecbuf + b * CAP);
  for (int i = t; 4 * i < cnt; i += 1024) {
    int4 v = ep4[i];
    int base = 4 * i;
#pragma unroll
    for (int k = 0; k < 4; k++) {
      int pk = (k == 0) ? v.x : (k == 1) ? v.y : (k == 2) ? v.z : v.w;
      if (base + k < cnt) {
        float2 s = v2[pk >> PBITS];
        int l = pk & (PSIZE - 1);
        atomicAdd(&ax[l], s.x);
        atomicAdd(&ay[l], s.y);
      }
    }
  }
  __syncthreads();
  if (t < PSIZE) {
    const int node = (b << PBITS) + t;
    if (node < NODES) {
      float d = dv[node];
      float sc = d * d;
      float2 vs = v2[node];
      z[node] = make_float2(sc * (ax[t] + vs.x), sc * (ay[t] + vs.y));
    }
  }
}

// ---------------------------------------------------------------------------
// K4: hop 2 + bias + log_softmax. 1024 thr.
__global__ __launch_bounds__(1024) void hop2_kernel(
    const int* __restrict__ cursor, const int* __restrict__ ecbuf,
    const float2* __restrict__ z, const float* __restrict__ dv,
    const float* __restrict__ bias, float2* __restrict__ out) {
  __shared__ float ax[PSIZE];
  __shared__ float ay[PSIZE];
  const int b = blockIdx.x;
  const int t = threadIdx.x;
  if (t < PSIZE) {
    ax[t] = 0.f;
    ay[t] = 0.f;
  }
  __syncthreads();
  const int cnt = min(cursor[b], CAP);
  const int4* ep4 = (const int4*)(ecbuf + b * CAP);
  for (int i = t; 4 * i < cnt; i += 1024) {
    int4 v = ep4[i];
    int base = 4 * i;
#pragma unroll
    for (int k = 0; k < 4; k++) {
      int pk = (k == 0) ? v.x : (k == 1) ? v.y : (k == 2) ? v.z : v.w;
      if (base + k < cnt) {
        float2 zv = z[pk >> PBITS];
        int l = pk & (PSIZE - 1);
        atomicAdd(&ax[l], zv.x);
        atomicAdd(&ay[l], zv.y);
      }
    }
  }
  __syncthreads();
  if (t < PSIZE) {
    const int node = (b << PBITS) + t;
    if (node < NODES) {
      float d = dv[node];
      float2 zi = z[node];
      float l0 = d * (ax[t] + zi.x) + bias[0];
      float l1 = d * (ay[t] + zi.y) + bias[1];
      float m = fmaxf(l0, l1);
      float ls = m + logf(expf(l0 - m) + expf(l1 - m));
      out[node] = make_float2(l0 - ls, l1 - ls);
    }
  }
}

// ---------------------------------------------------------------------------
extern "C" void kernel_launch(void* const* d_in, const int* in_sizes, int n_in,
                              void* d_out, int out_size, void* d_ws,
                              size_t ws_size, hipStream_t stream) {
  const float* x = (const float*)d_in[0];
  const void* ei = d_in[1];
  const float* W = (const float*)d_in[2];
  const float* bias = (const float*)d_in[3];
  float2* out = (float2*)d_out;

  char* w = (char*)d_ws;
  size_t off = 0;
  auto alloc = [&](size_t bytes) -> char* {
    char* p = w + off;
    off += (bytes + 255) & ~(size_t)255;
    return p;
  };
  const int NPAD = P_BUCKETS << PBITS;  // 100096
  int* cursor = (int*)alloc(P_BUCKETS * sizeof(int));
  int* ecbuf = (int*)alloc((size_t)P_BUCKETS * CAP * sizeof(int));  // 12.8 MB
  float2* u = (float2*)alloc((size_t)NPAD * sizeof(float2));
  float2* v2 = (float2*)alloc((size_t)NPAD * sizeof(float2));
  float* dv = (float*)alloc((size_t)NPAD * sizeof(float));
  float2* z = (float2*)alloc((size_t)NPAD * sizeof(float2));
  (void)ws_size;

  zero_kernel<<<1, 512, 0, stream>>>(cursor);
  partproj_kernel<<<K1_BLOCKS, 256, 0, stream>>>(ei, cursor, ecbuf, x, W, u);
  deg_kernel<<<P_BUCKETS, 1024, 0, stream>>>(cursor, ecbuf, u, v2, dv);
  hop1_kernel<<<P_BUCKETS, 1024, 0, stream>>>(cursor, ecbuf, v2, dv, z);
  hop2_kernel<<<P_BUCKETS, 1024, 0, stream>>>(cursor, ecbuf, z, dv, bias, out);
}

// Round 12
// 151.102 us; speedup vs baseline: 1.1521x; 1.1521x over previous
//
#include <hip/hip_runtime.h>
#include <hip/hip_bf16.h>
#include <math.h>

// GCN 2-hop + linear(64->2) + log_softmax, N=100000, E=1600000, D=64.
//
// R11 lessons: (1) nontemporal scattered stores = 8x HBM write amplification
// (54MB for 6.4MB payload) -> all scatter writes must stay line-coalescible
// in L2. (2) 1024-thr hop blocks regressed vs 256 (idle epilogue lanes, LDS
// collisions). R12: block-private DENSE edge windows -- each partition block
// owns exactly 6250 edges, bucket-sorts them into its own 25KB region (L2
// accumulates full lines -> 6.4MB clean write), no global cursor, no memset.
// Hops read per-(bucket,block) segments via a per-block scan row; scattered
// READS are L3-served and cheap, scattered WRITES are gone.
//
// Math (verified R8-R11): u = x@W^T; d = rsqrt(indeg+1); v = d*u;
//   z = d^2*(v_self + sum v_src); logit = d*(z_self + sum z_src)+b;
//   out = log_softmax(logit).

#define NODES 100000
#define EDGES 1600000
#define DIM 64

#define PBITS 8
#define PSIZE 256
#define P_BUCKETS 391  // ceil(100000/256)

#define PART_BLOCKS 256
#define ECHUNK (EDGES / PART_BLOCKS)  // 6250 edges per block window
#define PART_PAIRS (ECHUNK / 2)       // 3125
#define SCANW (P_BUCKETS + 1)         // 392 scan entries per block row

#define PROJ_BLOCKS 782
#define NODES_PER_PROJ 128
#define K1_BLOCKS (PART_BLOCKS + PROJ_BLOCKS)

// ---------------------------------------------------------------------------
// K1: role-split. Blocks [0,256): partition into block-private dense windows.
// Blocks [256,1038): projection u = x @ W^T.
__global__ __launch_bounds__(256) void partproj_kernel(
    const void* __restrict__ ei, int* __restrict__ bscan,
    int* __restrict__ eloc, const float* __restrict__ x,
    const float* __restrict__ W, float2* __restrict__ u) {
  const int t = threadIdx.x;
  if (blockIdx.x < PART_BLOCKS) {
    // ---------------- partition role ----------------
    __shared__ int sMode;
    __shared__ int lcnt[P_BUCKETS];
    __shared__ int sA[512];
    __shared__ int sB[512];
    if (t < 64) {
      const int* p = (const int*)ei;
      unsigned long long ball = __ballot(p[2 * t + 1] == 0);
      if (t == 0) sMode = (ball == ~0ULL) ? 1 : 0;
    }
    for (int i = t; i < P_BUCKETS; i += 256) lcnt[i] = 0;
    __syncthreads();
    const int m = sMode;
    const int blk = blockIdx.x;
    const int pbase = blk * PART_PAIRS;

    // pass 1: count targets into LDS
    if (m) {
      const longlong2* cp =
          (const longlong2*)((const long long*)ei + EDGES) + pbase;
      for (int i = t; i < PART_PAIRS; i += 256) {
        longlong2 v = cp[i];
        atomicAdd(&lcnt[((int)v.x) >> PBITS], 1);
        atomicAdd(&lcnt[((int)v.y) >> PBITS], 1);
      }
    } else {
      const int2* cp = (const int2*)((const int*)ei + EDGES) + pbase;
      for (int i = t; i < PART_PAIRS; i += 256) {
        int2 v = cp[i];
        atomicAdd(&lcnt[v.x >> PBITS], 1);
        atomicAdd(&lcnt[v.y >> PBITS], 1);
      }
    }
    __syncthreads();

    // inclusive Hillis-Steele scan of lcnt (padded to 512), ping-pong LDS
    for (int i = t; i < 512; i += 256) sA[i] = (i < P_BUCKETS) ? lcnt[i] : 0;
    __syncthreads();
    int* srcb = sA;
    int* dstb = sB;
    for (int off = 1; off < 512; off <<= 1) {
      for (int i = t; i < 512; i += 256)
        dstb[i] = srcb[i] + ((i >= off) ? srcb[i - off] : 0);
      __syncthreads();
      int* tmp = srcb;
      srcb = dstb;
      dstb = tmp;
    }
    // srcb = inclusive scan; excl(i) = i ? srcb[i-1] : 0; excl(391) = total.
    // write this block's scan row (coalesced 1.5KB)
    for (int i = t; i < SCANW; i += 256)
      bscan[blk * SCANW + i] = i ? srcb[i - 1] : 0;
    // reset lcnt as rank cursors
    for (int i = t; i < P_BUCKETS; i += 256) lcnt[i] = 0;
    __syncthreads();

    // pass 2: scatter packed edges into block-private dense window.
    // All writes land in a 25KB region -> L2 lines fill completely.
    int* myloc = eloc + blk * ECHUNK;
    if (m) {
      const longlong2* rp = (const longlong2*)ei + pbase;
      const longlong2* cp =
          (const longlong2*)((const long long*)ei + EDGES) + pbase;
      for (int i = t; i < PART_PAIRS; i += 256) {
        longlong2 rv = rp[i];
        longlong2 cv = cp[i];
        {
          int r = (int)rv.x, c = (int)cv.x, bk = c >> PBITS;
          int pos = (bk ? srcb[bk - 1] : 0) + atomicAdd(&lcnt[bk], 1);
          myloc[pos] = (r << PBITS) | (c & (PSIZE - 1));
        }
        {
          int r = (int)rv.y, c = (int)cv.y, bk = c >> PBITS;
          int pos = (bk ? srcb[bk - 1] : 0) + atomicAdd(&lcnt[bk], 1);
          myloc[pos] = (r << PBITS) | (c & (PSIZE - 1));
        }
      }
    } else {
      const int2* rp = (const int2*)ei + pbase;
      const int2* cp = (const int2*)((const int*)ei + EDGES) + pbase;
      for (int i = t; i < PART_PAIRS; i += 256) {
        int2 rv = rp[i];
        int2 cv = cp[i];
        {
          int bk = cv.x >> PBITS;
          int pos = (bk ? srcb[bk - 1] : 0) + atomicAdd(&lcnt[bk], 1);
          myloc[pos] = (rv.x << PBITS) | (cv.x & (PSIZE - 1));
        }
        {
          int bk = cv.y >> PBITS;
          int pos = (bk ? srcb[bk - 1] : 0) + atomicAdd(&lcnt[bk], 1);
          myloc[pos] = (rv.y << PBITS) | (cv.y & (PSIZE - 1));
        }
      }
    }
  } else {
    // ---------------- projection role: u[i] = x[i] @ W^T ----------------
    const int nbase = (blockIdx.x - PART_BLOCKS) * NODES_PER_PROJ;
    const int lane16 = t & 15;  // feature quad within node
    const int sub = t >> 4;     // 16 node-slots per pass
    const float4 w0 = *(const float4*)&W[lane16 * 4];
    const float4 w1 = *(const float4*)&W[DIM + lane16 * 4];
    for (int k = sub; k < NODES_PER_PROJ; k += 16) {
      const int node = nbase + k;
      if (node < NODES) {  // uniform within each 16-lane group
        float4 xv = *(const float4*)&x[(size_t)node * DIM + lane16 * 4];
        float p0 = xv.x * w0.x + xv.y * w0.y + xv.z * w0.z + xv.w * w0.w;
        float p1 = xv.x * w1.x + xv.y * w1.y + xv.z * w1.z + xv.w * w1.w;
#pragma unroll
        for (int off = 8; off >= 1; off >>= 1) {
          p0 += __shfl_xor(p0, off, 16);
          p1 += __shfl_xor(p1, off, 16);
        }
        if (lane16 == 0) u[node] = make_float2(p0, p1);
      }
    }
  }
}

// ---------------------------------------------------------------------------
// K2: degree + fold. One block per bucket, 512 thr (2 per block-segment).
__global__ __launch_bounds__(512) void degv_kernel(
    const int* __restrict__ bscan, const int* __restrict__ eloc,
    const float2* __restrict__ u, float2* __restrict__ v2,
    float* __restrict__ dv) {
  __shared__ int h[PSIZE];
  const int b = blockIdx.x;
  const int t = threadIdx.x;
  if (t < PSIZE) h[t] = 0;
  __syncthreads();
  const int s = t >> 1, j = t & 1;  // segment (part-block) s, half j
  const int s0 = bscan[s * SCANW + b];
  const int s1 = bscan[s * SCANW + b + 1];
  const int* ep = eloc + s * ECHUNK;
  for (int e = s0 + j; e < s1; e += 2) atomicAdd(&h[ep[e] & (PSIZE - 1)], 1);
  __syncthreads();
  if (t < PSIZE) {
    const int node = (b << PBITS) + t;
    if (node < NODES) {
      float d = rsqrtf((float)(h[t] + 1));
      float2 uu = u[node];
      dv[node] = d;
      v2[node] = make_float2(d * uu.x, d * uu.y);
    }
  }
}

// ---------------------------------------------------------------------------
// K3: hop 1. z = d^2 * (v_self + sum v_src).
__global__ __launch_bounds__(512) void hop1_kernel(
    const int* __restrict__ bscan, const int* __restrict__ eloc,
    const float2* __restrict__ v2, const float* __restrict__ dv,
    float2* __restrict__ z) {
  __shared__ float ax[PSIZE];
  __shared__ float ay[PSIZE];
  const int b = blockIdx.x;
  const int t = threadIdx.x;
  if (t < PSIZE) {
    ax[t] = 0.f;
    ay[t] = 0.f;
  }
  __syncthreads();
  const int s = t >> 1, j = t & 1;
  const int s0 = bscan[s * SCANW + b];
  const int s1 = bscan[s * SCANW + b + 1];
  const int* ep = eloc + s * ECHUNK;
  for (int e = s0 + j; e < s1; e += 2) {
    int pk = ep[e];
    float2 v = v2[pk >> PBITS];
    int l = pk & (PSIZE - 1);
    atomicAdd(&ax[l], v.x);
    atomicAdd(&ay[l], v.y);
  }
  __syncthreads();
  if (t < PSIZE) {
    const int node = (b << PBITS) + t;
    if (node < NODES) {
      float d = dv[node];
      float sc = d * d;
      float2 vs = v2[node];
      z[node] = make_float2(sc * (ax[t] + vs.x), sc * (ay[t] + vs.y));
    }
  }
}

// ---------------------------------------------------------------------------
// K4: hop 2 + bias + log_softmax.
__global__ __launch_bounds__(512) void hop2_kernel(
    const int* __restrict__ bscan, const int* __restrict__ eloc,
    const float2* __restrict__ z, const float* __restrict__ dv,
    const float* __restrict__ bias, float2* __restrict__ out) {
  __shared__ float ax[PSIZE];
  __shared__ float ay[PSIZE];
  const int b = blockIdx.x;
  const int t = threadIdx.x;
  if (t < PSIZE) {
    ax[t] = 0.f;
    ay[t] = 0.f;
  }
  __syncthreads();
  const int s = t >> 1, j = t & 1;
  const int s0 = bscan[s * SCANW + b];
  const int s1 = bscan[s * SCANW + b + 1];
  const int* ep = eloc + s * ECHUNK;
  for (int e = s0 + j; e < s1; e += 2) {
    int pk = ep[e];
    float2 zv = z[pk >> PBITS];
    int l = pk & (PSIZE - 1);
    atomicAdd(&ax[l], zv.x);
    atomicAdd(&ay[l], zv.y);
  }
  __syncthreads();
  if (t < PSIZE) {
    const int node = (b << PBITS) + t;
    if (node < NODES) {
      float d = dv[node];
      float2 zi = z[node];
      float l0 = d * (ax[t] + zi.x) + bias[0];
      float l1 = d * (ay[t] + zi.y) + bias[1];
      float m = fmaxf(l0, l1);
      float ls = m + logf(expf(l0 - m) + expf(l1 - m));
      out[node] = make_float2(l0 - ls, l1 - ls);
    }
  }
}

// ---------------------------------------------------------------------------
extern "C" void kernel_launch(void* const* d_in, const int* in_sizes, int n_in,
                              void* d_out, int out_size, void* d_ws,
                              size_t ws_size, hipStream_t stream) {
  const float* x = (const float*)d_in[0];
  const void* ei = d_in[1];
  const float* W = (const float*)d_in[2];
  const float* bias = (const float*)d_in[3];
  float2* out = (float2*)d_out;

  char* w = (char*)d_ws;
  size_t off = 0;
  auto alloc = [&](size_t bytes) -> char* {
    char* p = w + off;
    off += (bytes + 255) & ~(size_t)255;
    return p;
  };
  const int NPAD = P_BUCKETS << PBITS;  // 100096
  int* bscan = (int*)alloc((size_t)PART_BLOCKS * SCANW * sizeof(int));  // 400KB
  int* eloc = (int*)alloc((size_t)EDGES * sizeof(int));                 // 6.4MB
  float2* u = (float2*)alloc((size_t)NPAD * sizeof(float2));
  float2* v2 = (float2*)alloc((size_t)NPAD * sizeof(float2));
  float* dv = (float*)alloc((size_t)NPAD * sizeof(float));
  float2* z = (float2*)alloc((size_t)NPAD * sizeof(float2));
  (void)ws_size;

  partproj_kernel<<<K1_BLOCKS, 256, 0, stream>>>(ei, bscan, eloc, x, W, u);
  degv_kernel<<<P_BUCKETS, 512, 0, stream>>>(bscan, eloc, u, v2, dv);
  hop1_kernel<<<P_BUCKETS, 512, 0, stream>>>(bscan, eloc, v2, dv, z);
  hop2_kernel<<<P_BUCKETS, 512, 0, stream>>>(bscan, eloc, z, dv, bias, out);
}